// Round 2
// baseline (485.165 us; speedup 1.0000x reference)
//
#include <hip/hip_runtime.h>
#include <math.h>

#define NB 8
#define NC 128
#define NPOS 2000
#define NK 32000
#define IN_EPS 1e-3f
#define BN_EPS 1e-5f

typedef short bf16x8 __attribute__((ext_vector_type(8)));
typedef _Float16 f16x8 __attribute__((ext_vector_type(8)));
typedef float f32x4 __attribute__((ext_vector_type(4)));
typedef unsigned short ushort_t;
typedef unsigned int uint_t;

// LDS row stride in ushorts (128 payload + 8 pad; keeps 16B alignment, 272B rows)
#define XSTRIDE 136

// ---- workspace layout ----
// [0 .. 32768)      sumP  : 32 buckets x (8b x 128c), bucket-major   (floats)
// [32768 .. 65536)  sqP
// [65536 .. 66560)  alpha
// [66560 .. 67584)  beta
// byte 270336:      weights w0(bf16),wq,wk,wv (16384 ushorts each)
// byte 401408:      h buffer: [b][pos][136] fp16 (padded rows, 272B each)
#define WSF_SUMP  0
#define WSF_SQP   32768
#define WSF_ALPHA 65536
#define WSF_BETA  66560
#define WSB_WEIGHTS 270336
#define WSB_H     401408
#define WS_NEEDED ((size_t)WSB_H + (size_t)NB * NK * XSTRIDE * 2)

__device__ __forceinline__ f32x4 mfma_bf16(bf16x8 a, bf16x8 b, f32x4 c) {
  return __builtin_amdgcn_mfma_f32_16x16x32_bf16(a, b, c, 0, 0, 0);
}
__device__ __forceinline__ f32x4 mfma_f16(f16x8 a, f16x8 b, f32x4 c) {
  return __builtin_amdgcn_mfma_f32_16x16x32_f16(a, b, c, 0, 0, 0);
}

// fp32 -> bf16 round-to-nearest-even
__device__ __forceinline__ ushort_t f2bf(float f) {
  unsigned u = __float_as_uint(f);
  return (ushort_t)((u + 0x7FFFu + ((u >> 16) & 1u)) >> 16);
}
__device__ __forceinline__ ushort_t f2h(float f) {
  union { _Float16 h; ushort_t u; } cv;
  cv.h = (_Float16)f;
  return cv.u;
}
__device__ __forceinline__ float h2f(ushort_t u) {
  union { _Float16 h; ushort_t u; } cv;
  cv.u = u;
  return (float)cv.h;
}

// ---------------- K0: cast weights (w0 -> bf16; qkv -> fp16 when QKV_F16) ----------------
template <int QKV_F16>
__global__ __launch_bounds__(256) void k_prep(const float* __restrict__ w0,
    const float* __restrict__ wq, const float* __restrict__ wk,
    const float* __restrict__ wv, ushort_t* __restrict__ wb) {
  int idx = blockIdx.x * 256 + threadIdx.x;  // 0..65535
  int m = idx >> 14;
  int e = idx & 16383;
  const float* src = (m == 0) ? w0 : (m == 1) ? wq : (m == 2) ? wk : wv;
  float v = src[e];
  wb[m * 16384 + e] = (QKV_F16 && m != 0) ? f2h(v) : f2bf(v);
}

// ---- staging: Xt[col][cin] bf16 into LDS, 128 columns (v1 fallback) ----
__device__ __forceinline__ void stage_xt128(const float* __restrict__ xb,
                                            ushort_t* __restrict__ xt, int tid) {
  const int col = tid & 127;
  const int hi = tid >> 7;  // 0/1
  const float* p = xb + col;
#pragma unroll
  for (int i = 0; i < 8; ++i) {
    const int c0 = hi * 64 + i * 8;
    ushort_t u[8] __attribute__((aligned(16)));
#pragma unroll
    for (int j = 0; j < 8; ++j) u[j] = f2bf(p[(size_t)(c0 + j) * NK]);
    *(uint4*)(xt + col * XSTRIDE + c0) = *(const uint4*)u;
  }
}

// ---- staging: 64 columns ----
__device__ __forceinline__ void stage_xt64(const float* __restrict__ xb,
                                           ushort_t* __restrict__ xt, int tid) {
  const int col = tid & 63;
  const int hi = tid >> 6;  // 0..3
  const float* p = xb + col;
#pragma unroll
  for (int i = 0; i < 4; ++i) {
    const int c0 = hi * 32 + i * 8;
    ushort_t u[8] __attribute__((aligned(16)));
#pragma unroll
    for (int j = 0; j < 8; ++j) u[j] = f2bf(p[(size_t)(c0 + j) * NK]);
    *(uint4*)(xt + col * XSTRIDE + c0) = *(const uint4*)u;
  }
}

// ---------------- K1 v2: conv + stats + materialize h (fp16, padded rows) ----------------
// 64-pos tile, 18.4KB LDS -> 8 blocks/CU. MFMA in W x X orientation:
// D col = lane&15 -> position, row = quad*4+r -> ch-in-strip (verified v1 H-phase code).
// Stats computed from the fp16-ROUNDED h so alpha/beta are consistent with stored data
// (keeps the BN-mean==0 identity used by k_fold).
__global__ __launch_bounds__(256, 8) void k_stats2(const float* __restrict__ x,
    const ushort_t* __restrict__ w0b, float* __restrict__ sumP,
    float* __restrict__ sqP, ushort_t* __restrict__ hg) {
  __shared__ ushort_t xt[64 * XSTRIDE] __attribute__((aligned(16)));
  __shared__ float ssum[128], ssq[128];
  const int b = blockIdx.y;
  const int tid = threadIdx.x;
  stage_xt64(x + (size_t)b * NC * NK + (size_t)blockIdx.x * 64, xt, tid);
  __syncthreads();
  const int lane = tid & 63, w = tid >> 6;
  const int m = lane & 15, quad = lane >> 4;
  ushort_t* hrow0 = hg + ((size_t)b * NK + (size_t)blockIdx.x * 64) * XSTRIDE;

#pragma unroll 1
  for (int p = 0; p < 2; ++p) {
    const int ch0 = (w + p * 4) * 16;
    bf16x8 wf[4];
#pragma unroll
    for (int kb = 0; kb < 4; ++kb)
      wf[kb] = *(const bf16x8*)(w0b + (ch0 + m) * 128 + kb * 32 + quad * 8);
    float s0 = 0.f, s1 = 0.f, s2 = 0.f, s3 = 0.f;
    float q0 = 0.f, q1 = 0.f, q2 = 0.f, q3 = 0.f;
#pragma unroll
    for (int t = 0; t < 4; ++t) {
      const ushort_t* xr = xt + (t * 16 + m) * XSTRIDE;
      f32x4 acc = {0.f, 0.f, 0.f, 0.f};
#pragma unroll
      for (int kb = 0; kb < 4; ++kb) {
        bf16x8 bx = *(const bf16x8*)(xr + kb * 32 + quad * 8);
        acc = mfma_bf16(wf[kb], bx, acc);
      }
      const ushort_t u0 = f2h(acc[0]), u1 = f2h(acc[1]);
      const ushort_t u2 = f2h(acc[2]), u3 = f2h(acc[3]);
      uint2 pk;
      pk.x = (uint_t)u0 | ((uint_t)u1 << 16);
      pk.y = (uint_t)u2 | ((uint_t)u3 << 16);
      *(uint2*)(hrow0 + (size_t)(t * 16 + m) * XSTRIDE + ch0 + quad * 4) = pk;
      const float r0 = h2f(u0), r1 = h2f(u1), r2 = h2f(u2), r3 = h2f(u3);
      s0 += r0; s1 += r1; s2 += r2; s3 += r3;
      q0 = fmaf(r0, r0, q0); q1 = fmaf(r1, r1, q1);
      q2 = fmaf(r2, r2, q2); q3 = fmaf(r3, r3, q3);
    }
    // positions live across the 16 m-lanes: butterfly over lane bits 0..3
#pragma unroll
    for (int d = 1; d < 16; d <<= 1) {
      s0 += __shfl_xor(s0, d); s1 += __shfl_xor(s1, d);
      s2 += __shfl_xor(s2, d); s3 += __shfl_xor(s3, d);
      q0 += __shfl_xor(q0, d); q1 += __shfl_xor(q1, d);
      q2 += __shfl_xor(q2, d); q3 += __shfl_xor(q3, d);
    }
    if (m == 0) {  // strips disjoint across (w,p,quad) -> plain stores
      ssum[ch0 + quad * 4 + 0] = s0; ssum[ch0 + quad * 4 + 1] = s1;
      ssum[ch0 + quad * 4 + 2] = s2; ssum[ch0 + quad * 4 + 3] = s3;
      ssq[ch0 + quad * 4 + 0] = q0; ssq[ch0 + quad * 4 + 1] = q1;
      ssq[ch0 + quad * 4 + 2] = q2; ssq[ch0 + quad * 4 + 3] = q3;
    }
  }
  __syncthreads();
  if (tid < 128) {
    const int bucket = blockIdx.x & 31;
    atomicAdd(&sumP[bucket * 1024 + b * 128 + tid], ssum[tid]);
    atomicAdd(&sqP[bucket * 1024 + b * 128 + tid], ssq[tid]);
  }
}

// ---------------- K2: reduce buckets, fold IN+BN into per-(b,c) alpha/beta ----------------
__global__ void k_fold(const float* __restrict__ ws_in, const float* __restrict__ bn_g,
                       const float* __restrict__ bn_b, float* __restrict__ alpha,
                       float* __restrict__ beta) {
  int c = threadIdx.x;  // 128 threads
  const float* sumP = ws_in + WSF_SUMP;
  const float* sqP = ws_in + WSF_SQP;
  float var[NB], muv[NB];
  float bvar = 0.f;
#pragma unroll 1
  for (int b = 0; b < NB; ++b) {
    float s = 0.f, q = 0.f;
#pragma unroll
    for (int k = 0; k < 32; ++k) {
      s += sumP[k * 1024 + b * 128 + c];
      q += sqP[k * 1024 + b * 128 + c];
    }
    float mu = s * (1.f / NK);
    float v = q * (1.f / NK) - mu * mu;
    muv[b] = mu;
    var[b] = v;
    bvar += v / (v + IN_EPS);
  }
  bvar *= 0.125f;
  float s2 = rsqrtf(bvar + BN_EPS);
  float g = bn_g[c], bb = bn_b[c];
#pragma unroll
  for (int b = 0; b < NB; ++b) {
    float a = rsqrtf(var[b] + IN_EPS) * s2 * g;
    alpha[b * 128 + c] = a;
    beta[b * 128 + c] = bb - muv[b] * a;
  }
}

// ---------------- K3 v2: load h -> in-LDS norm -> qkv+softmax+agg (fp16 MFMA) ----------------
// 19,968B LDS + <=64 VGPR -> 8 blocks/CU. Tile load is one contiguous 17,408B
// coalesced copy (h stored pre-padded to the LDS row stride).
__global__ __launch_bounds__(256, 8) void k_fused2(
    const ushort_t* __restrict__ hg, const float* __restrict__ x_row,
    const ushort_t* __restrict__ wb, const float* __restrict__ alpha,
    const float* __restrict__ beta, const float* __restrict__ bq,
    const float* __restrict__ bk, const float* __restrict__ bv,
    const float* __restrict__ g1p, float* __restrict__ out) {
  __shared__ ushort_t xt[64 * XSTRIDE] __attribute__((aligned(16)));  // 17408 B
  __shared__ float souts[128 * 5];                                    // 2560 B
  const int b = blockIdx.y;
  const int tid = threadIdx.x;
  const int lane = tid & 63, w = tid >> 6;

  // stage: 1088 uint4s (17,408 B), contiguous & coalesced, reg-staged
  {
    const uint4* src =
        (const uint4*)(hg + ((size_t)b * NK + (size_t)blockIdx.x * 64) * XSTRIDE);
    uint4* dst = (uint4*)xt;
#pragma unroll
    for (int i = 0; i < 4; ++i) dst[i * 256 + tid] = src[i * 256 + tid];
    if (tid < 64) dst[1024 + tid] = src[1024 + tid];
  }
  const float g1 = g1p[0];
  __syncthreads();

  // ---- in-LDS normalization: h = relu(alpha*h + beta), fp16 in/out ----
  {
    const int pos = tid & 63;
    const int cg = __builtin_amdgcn_readfirstlane(tid >> 6);  // wave-uniform
    ushort_t* row = xt + pos * XSTRIDE + cg * 32;
    const float* ap = alpha + b * 128 + cg * 32;
    const float* bp = beta + b * 128 + cg * 32;
#pragma unroll
    for (int i = 0; i < 4; ++i) {
      uint4 v = *(const uint4*)(row + i * 8);
      uint_t rr[4] = {v.x, v.y, v.z, v.w};
      uint_t ow[4];
#pragma unroll
      for (int j = 0; j < 4; ++j) {
        const int c = i * 8 + j * 2;
        float lo = h2f((ushort_t)(rr[j] & 0xffffu));
        float hi = h2f((ushort_t)(rr[j] >> 16));
        float nlo = fmaxf(fmaf(lo, ap[c], bp[c]), 0.f);
        float nhi = fmaxf(fmaf(hi, ap[c + 1], bp[c + 1]), 0.f);
        ow[j] = (uint_t)f2h(nlo) | ((uint_t)f2h(nhi) << 16);
      }
      uint4 o;
      o.x = ow[0]; o.y = ow[1]; o.z = ow[2]; o.w = ow[3];
      *(uint4*)(row + i * 8) = o;
    }
  }
  __syncthreads();

  // ---- QKV phase (fp16) ----
  const int m = lane & 15, quad = lane >> 4;
  const ushort_t* wqb = wb + 16384;
  const ushort_t* wkb = wb + 32768;
  const ushort_t* wvb = wb + 49152;
#pragma unroll 1
  for (int p = 0; p < 2; ++p) {
    const int ch0 = (w + p * 4) * 16;
    f16x8 wqf[4], wkf[4], wvf[4];
#pragma unroll
    for (int kb = 0; kb < 4; ++kb) {
      wqf[kb] = *(const f16x8*)(wqb + (ch0 + m) * 128 + kb * 32 + quad * 8);
      wkf[kb] = *(const f16x8*)(wkb + (ch0 + m) * 128 + kb * 32 + quad * 8);
      wvf[kb] = *(const f16x8*)(wvb + (ch0 + m) * 128 + kb * 32 + quad * 8);
    }
    const float bqv = bq[ch0 + m];
    const float bkv = bk[ch0 + m];
    const float bvv = bv[ch0 + m];
#pragma unroll 1
    for (int t = 0; t < 4; ++t) {
      const ushort_t* hr = xt + (t * 16 + m) * XSTRIDE;
      f16x8 af[4];
#pragma unroll
      for (int kb = 0; kb < 4; ++kb)
        af[kb] = *(const f16x8*)(hr + kb * 32 + quad * 8);
      f32x4 qa = {0.f, 0.f, 0.f, 0.f};
      f32x4 ka = {0.f, 0.f, 0.f, 0.f};
#pragma unroll
      for (int kb = 0; kb < 4; ++kb) qa = mfma_f16(af[kb], wqf[kb], qa);
#pragma unroll
      for (int kb = 0; kb < 4; ++kb) ka = mfma_f16(af[kb], wkf[kb], ka);
      // D: col=lane&15 -> outch-in-strip, row=quad*4+r -> neighbor
      float p0 = (qa[0] + bqv) * (ka[0] + bkv);
      float p1 = (qa[1] + bqv) * (ka[1] + bkv);
      float p2 = (qa[2] + bqv) * (ka[2] + bkv);
      float p3 = (qa[3] + bqv) * (ka[3] + bkv);
      float mx = fmaxf(fmaxf(p0, p1), fmaxf(p2, p3));
      mx = fmaxf(mx, __shfl_xor(mx, 16));
      mx = fmaxf(mx, __shfl_xor(mx, 32));
      float e0 = __expf(p0 - mx), e1 = __expf(p1 - mx);
      float e2 = __expf(p2 - mx), e3 = __expf(p3 - mx);
      float sm = (e0 + e1) + (e2 + e3);
      sm += __shfl_xor(sm, 16);
      sm += __shfl_xor(sm, 32);
      f32x4 va = {0.f, 0.f, 0.f, 0.f};
#pragma unroll
      for (int kb = 0; kb < 4; ++kb) va = mfma_f16(af[kb], wvf[kb], va);
      float r0 = e0 * (va[0] + bvv) + e1 * (va[1] + bvv) +
                 e2 * (va[2] + bvv) + e3 * (va[3] + bvv);
      r0 += __shfl_xor(r0, 16);
      r0 += __shfl_xor(r0, 32);
      if (quad == 0) souts[(ch0 + m) * 5 + t] = r0 / sm;
    }
  }
  __syncthreads();

  // ---- coalesced epilogue: out = x_row + g1 * souts ----
  if (tid < 128) {
    const int c = tid;
    const size_t oi = ((size_t)b * NC + c) * NPOS + blockIdx.x * 4;
    const float4 xr = *(const float4*)(x_row + oi);
    const float* sp = souts + c * 5;
    float4 o;
    o.x = xr.x + g1 * sp[0];
    o.y = xr.y + g1 * sp[1];
    o.z = xr.z + g1 * sp[2];
    o.w = xr.w + g1 * sp[3];
    *(float4*)(out + oi) = o;
  }
}

// =================== v1 fallback path (used only if workspace too small) ===================
__global__ __launch_bounds__(256, 4) void k_stats1(const float* __restrict__ x,
    const ushort_t* __restrict__ w0b, float* __restrict__ sumP,
    float* __restrict__ sqP) {
  __shared__ ushort_t xt[128 * XSTRIDE];
  __shared__ float ssum[128], ssq[128];
  const int b = blockIdx.y;
  const int tid = threadIdx.x;
  stage_xt128(x + (size_t)b * NC * NK + (size_t)blockIdx.x * 128, xt, tid);
  __syncthreads();
  const int lane = tid & 63, w = tid >> 6;
  const int m = lane & 15, quad = lane >> 4;

#pragma unroll 1
  for (int p = 0; p < 2; ++p) {
    const int ch0 = (w + p * 4) * 16;
    bf16x8 wf[4];
#pragma unroll
    for (int kb = 0; kb < 4; ++kb)
      wf[kb] = *(const bf16x8*)(w0b + (ch0 + m) * 128 + kb * 32 + quad * 8);
    float s = 0.f, q2 = 0.f;
#pragma unroll 2
    for (int t = 0; t < 8; ++t) {
      const ushort_t* xr = xt + (t * 16 + m) * XSTRIDE;
      f32x4 acc = {0.f, 0.f, 0.f, 0.f};
#pragma unroll
      for (int kb = 0; kb < 4; ++kb) {
        bf16x8 af = *(const bf16x8*)(xr + kb * 32 + quad * 8);
        acc = mfma_bf16(af, wf[kb], acc);
      }
      s += (acc[0] + acc[1]) + (acc[2] + acc[3]);
      q2 += (acc[0] * acc[0] + acc[1] * acc[1]) +
            (acc[2] * acc[2] + acc[3] * acc[3]);
    }
    s += __shfl_xor(s, 16);
    s += __shfl_xor(s, 32);
    q2 += __shfl_xor(q2, 16);
    q2 += __shfl_xor(q2, 32);
    if (quad == 0) {
      ssum[ch0 + m] = s;
      ssq[ch0 + m] = q2;
    }
  }
  __syncthreads();
  if (tid < 128) {
    const int bucket = blockIdx.x & 31;
    atomicAdd(&sumP[bucket * 1024 + b * 128 + tid], ssum[tid]);
    atomicAdd(&sqP[bucket * 1024 + b * 128 + tid], ssq[tid]);
  }
}

__global__ __launch_bounds__(256, 4) void k_fused1(const float* __restrict__ x,
    const float* __restrict__ x_row, const ushort_t* __restrict__ wb,
    const float* __restrict__ alpha, const float* __restrict__ beta,
    const float* __restrict__ bq, const float* __restrict__ bk,
    const float* __restrict__ bv, const float* __restrict__ g1p,
    float* __restrict__ out) {
  __shared__ ushort_t xt[64 * XSTRIDE];
  __shared__ ushort_t ht[64 * XSTRIDE];
  __shared__ float souts[128 * 5];
  const int b = blockIdx.y;
  const int tid = threadIdx.x;
  stage_xt64(x + (size_t)b * NC * NK + (size_t)blockIdx.x * 64, xt, tid);
  const float g1 = g1p[0];
  __syncthreads();
  const int lane = tid & 63, w = tid >> 6;
  const int m = lane & 15, quad = lane >> 4;
  const ushort_t* w0b = wb;
  const ushort_t* wqb = wb + 16384;
  const ushort_t* wkb = wb + 32768;
  const ushort_t* wvb = wb + 49152;

#pragma unroll 1
  for (int p = 0; p < 2; ++p) {
    const int ch0 = (w + p * 4) * 16;
    bf16x8 wf[4];
#pragma unroll
    for (int kb = 0; kb < 4; ++kb)
      wf[kb] = *(const bf16x8*)(w0b + (ch0 + m) * 128 + kb * 32 + quad * 8);
    const float4 av = *(const float4*)(alpha + b * 128 + ch0 + quad * 4);
    const float4 bev = *(const float4*)(beta + b * 128 + ch0 + quad * 4);
#pragma unroll
    for (int t = 0; t < 4; ++t) {
      const ushort_t* xr = xt + (t * 16 + m) * XSTRIDE;
      f32x4 acc = {0.f, 0.f, 0.f, 0.f};
#pragma unroll
      for (int kb = 0; kb < 4; ++kb) {
        bf16x8 bx = *(const bf16x8*)(xr + kb * 32 + quad * 8);
        acc = mfma_bf16(wf[kb], bx, acc);
      }
      float h0 = fmaxf(acc[0] * av.x + bev.x, 0.f);
      float h1 = fmaxf(acc[1] * av.y + bev.y, 0.f);
      float h2 = fmaxf(acc[2] * av.z + bev.z, 0.f);
      float h3 = fmaxf(acc[3] * av.w + bev.w, 0.f);
      uint2 pk;
      pk.x = (uint_t)f2bf(h0) | ((uint_t)f2bf(h1) << 16);
      pk.y = (uint_t)f2bf(h2) | ((uint_t)f2bf(h3) << 16);
      *(uint2*)(ht + (t * 16 + m) * XSTRIDE + ch0 + quad * 4) = pk;
    }
  }
  __syncthreads();

#pragma unroll 1
  for (int p = 0; p < 2; ++p) {
    const int ch0 = (w + p * 4) * 16;
    bf16x8 wqf[4], wkf[4], wvf[4];
#pragma unroll
    for (int kb = 0; kb < 4; ++kb) {
      wqf[kb] = *(const bf16x8*)(wqb + (ch0 + m) * 128 + kb * 32 + quad * 8);
      wkf[kb] = *(const bf16x8*)(wkb + (ch0 + m) * 128 + kb * 32 + quad * 8);
      wvf[kb] = *(const bf16x8*)(wvb + (ch0 + m) * 128 + kb * 32 + quad * 8);
    }
    const float bqv = bq[ch0 + m];
    const float bkv = bk[ch0 + m];
    const float bvv = bv[ch0 + m];
#pragma unroll 1
    for (int t = 0; t < 4; ++t) {
      const ushort_t* hr = ht + (t * 16 + m) * XSTRIDE;
      bf16x8 af[4];
#pragma unroll
      for (int kb = 0; kb < 4; ++kb)
        af[kb] = *(const bf16x8*)(hr + kb * 32 + quad * 8);
      f32x4 qa = {0.f, 0.f, 0.f, 0.f};
      f32x4 ka = {0.f, 0.f, 0.f, 0.f};
#pragma unroll
      for (int kb = 0; kb < 4; ++kb) qa = mfma_bf16(af[kb], wqf[kb], qa);
#pragma unroll
      for (int kb = 0; kb < 4; ++kb) ka = mfma_bf16(af[kb], wkf[kb], ka);
      float p0 = (qa[0] + bqv) * (ka[0] + bkv);
      float p1 = (qa[1] + bqv) * (ka[1] + bkv);
      float p2 = (qa[2] + bqv) * (ka[2] + bkv);
      float p3 = (qa[3] + bqv) * (ka[3] + bkv);
      float mx = fmaxf(fmaxf(p0, p1), fmaxf(p2, p3));
      mx = fmaxf(mx, __shfl_xor(mx, 16));
      mx = fmaxf(mx, __shfl_xor(mx, 32));
      float e0 = __expf(p0 - mx), e1 = __expf(p1 - mx);
      float e2 = __expf(p2 - mx), e3 = __expf(p3 - mx);
      float sm = (e0 + e1) + (e2 + e3);
      sm += __shfl_xor(sm, 16);
      sm += __shfl_xor(sm, 32);
      f32x4 va = {0.f, 0.f, 0.f, 0.f};
#pragma unroll
      for (int kb = 0; kb < 4; ++kb) va = mfma_bf16(af[kb], wvf[kb], va);
      float r0 = e0 * (va[0] + bvv) + e1 * (va[1] + bvv) +
                 e2 * (va[2] + bvv) + e3 * (va[3] + bvv);
      r0 += __shfl_xor(r0, 16);
      r0 += __shfl_xor(r0, 32);
      if (quad == 0) souts[(ch0 + m) * 5 + t] = r0 / sm;
    }
  }
  __syncthreads();

  if (tid < 128) {
    const int c = tid;
    const size_t oi = ((size_t)b * NC + c) * NPOS + blockIdx.x * 4;
    const float4 xr = *(const float4*)(x_row + oi);
    const float* sp = souts + c * 5;
    float4 o;
    o.x = xr.x + g1 * sp[0];
    o.y = xr.y + g1 * sp[1];
    o.z = xr.z + g1 * sp[2];
    o.w = xr.w + g1 * sp[3];
    *(float4*)(out + oi) = o;
  }
}

extern "C" void kernel_launch(void* const* d_in, const int* in_sizes, int n_in,
                              void* d_out, int out_size, void* d_ws, size_t ws_size,
                              hipStream_t stream) {
  (void)in_sizes; (void)n_in; (void)out_size;
  const float* x_row   = (const float*)d_in[0];
  const float* x_local = (const float*)d_in[1];
  const float* w0   = (const float*)d_in[2];
  const float* bn_g = (const float*)d_in[4];
  const float* bn_b = (const float*)d_in[5];
  const float* wq   = (const float*)d_in[6];
  const float* bq   = (const float*)d_in[7];
  const float* wk   = (const float*)d_in[8];
  const float* bk   = (const float*)d_in[9];
  const float* wv   = (const float*)d_in[10];
  const float* bv   = (const float*)d_in[11];
  const float* gamma1 = (const float*)d_in[12];
  float* out = (float*)d_out;
  float* ws = (float*)d_ws;
  ushort_t* wb = (ushort_t*)((char*)d_ws + WSB_WEIGHTS);
  ushort_t* hg = (ushort_t*)((char*)d_ws + WSB_H);

  hipMemsetAsync(ws, 0, 65536 * sizeof(float), stream);  // bucketed accumulators

  if (ws_size >= WS_NEEDED) {
    k_prep<1><<<256, 256, 0, stream>>>(w0, wq, wk, wv, wb);
    k_stats2<<<dim3(500, NB), 256, 0, stream>>>(x_local, wb, ws + WSF_SUMP,
                                                ws + WSF_SQP, hg);
    k_fold<<<1, 128, 0, stream>>>(ws, bn_g, bn_b, ws + WSF_ALPHA, ws + WSF_BETA);
    k_fused2<<<dim3(500, NB), 256, 0, stream>>>(hg, x_row, wb, ws + WSF_ALPHA,
                                                ws + WSF_BETA, bq, bk, bv, gamma1,
                                                out);
  } else {
    // workspace too small for the h buffer: previous verified pipeline
    k_prep<0><<<256, 256, 0, stream>>>(w0, wq, wk, wv, wb);
    k_stats1<<<dim3(250, NB), 256, 0, stream>>>(x_local, wb, ws + WSF_SUMP,
                                                ws + WSF_SQP);
    k_fold<<<1, 128, 0, stream>>>(ws, bn_g, bn_b, ws + WSF_ALPHA, ws + WSF_BETA);
    k_fused1<<<dim3(500, NB), 256, 0, stream>>>(x_local, x_row, wb, ws + WSF_ALPHA,
                                                ws + WSF_BETA, bq, bk, bv, gamma1,
                                                out);
  }
}

// Round 3
// 311.625 us; speedup vs baseline: 1.5569x; 1.5569x over previous
//
#include <hip/hip_runtime.h>
#include <math.h>

#define NB 8
#define NC 128
#define NPOS 2000
#define NK 32000
#define IN_EPS 1e-3f
#define BN_EPS 1e-5f

typedef short bf16x8 __attribute__((ext_vector_type(8)));
typedef _Float16 f16x8 __attribute__((ext_vector_type(8)));
typedef float f32x4 __attribute__((ext_vector_type(4)));
typedef unsigned short ushort_t;
typedef unsigned int uint_t;

// LDS row stride in ushorts (128 payload + 8 pad; keeps 16B alignment, 272B rows)
#define XSTRIDE 136

// ---- workspace layout ----
// [0 .. 32768)      sumP  : 32 buckets x (8b x 128c), bucket-major   (floats)
// [32768 .. 65536)  sqP
// [65536 .. 66560)  alpha
// [66560 .. 67584)  beta
// byte 270336:      weights w0(bf16),wq,wk,wv (16384 ushorts each)
// byte 401408:      h buffer: [b][pos][136] fp16 (padded rows, 272B each)
#define WSF_SUMP  0
#define WSF_SQP   32768
#define WSF_ALPHA 65536
#define WSF_BETA  66560
#define WSB_WEIGHTS 270336
#define WSB_H     401408
#define WS_NEEDED ((size_t)WSB_H + (size_t)NB * NK * XSTRIDE * 2)

__device__ __forceinline__ f32x4 mfma_bf16(bf16x8 a, bf16x8 b, f32x4 c) {
  return __builtin_amdgcn_mfma_f32_16x16x32_bf16(a, b, c, 0, 0, 0);
}
__device__ __forceinline__ f32x4 mfma_f16(f16x8 a, f16x8 b, f32x4 c) {
  return __builtin_amdgcn_mfma_f32_16x16x32_f16(a, b, c, 0, 0, 0);
}

// fp32 -> bf16 round-to-nearest-even
__device__ __forceinline__ ushort_t f2bf(float f) {
  unsigned u = __float_as_uint(f);
  return (ushort_t)((u + 0x7FFFu + ((u >> 16) & 1u)) >> 16);
}
__device__ __forceinline__ ushort_t f2h(float f) {
  union { _Float16 h; ushort_t u; } cv;
  cv.h = (_Float16)f;
  return cv.u;
}
__device__ __forceinline__ float h2f(ushort_t u) {
  union { _Float16 h; ushort_t u; } cv;
  cv.u = u;
  return (float)cv.h;
}

// ---------------- K0: cast weights (w0 -> bf16; qkv -> fp16 when QKV_F16) ----------------
template <int QKV_F16>
__global__ __launch_bounds__(256) void k_prep(const float* __restrict__ w0,
    const float* __restrict__ wq, const float* __restrict__ wk,
    const float* __restrict__ wv, ushort_t* __restrict__ wb) {
  int idx = blockIdx.x * 256 + threadIdx.x;  // 0..65535
  int m = idx >> 14;
  int e = idx & 16383;
  const float* src = (m == 0) ? w0 : (m == 1) ? wq : (m == 2) ? wk : wv;
  float v = src[e];
  wb[m * 16384 + e] = (QKV_F16 && m != 0) ? f2h(v) : f2bf(v);
}

// ---- staging: Xt[col][cin] bf16 into LDS, 128 columns (v1 fallback) ----
__device__ __forceinline__ void stage_xt128(const float* __restrict__ xb,
                                            ushort_t* __restrict__ xt, int tid) {
  const int col = tid & 127;
  const int hi = tid >> 7;  // 0/1
  const float* p = xb + col;
#pragma unroll
  for (int i = 0; i < 8; ++i) {
    const int c0 = hi * 64 + i * 8;
    ushort_t u[8] __attribute__((aligned(16)));
#pragma unroll
    for (int j = 0; j < 8; ++j) u[j] = f2bf(p[(size_t)(c0 + j) * NK]);
    *(uint4*)(xt + col * XSTRIDE + c0) = *(const uint4*)u;
  }
}

// ---- staging: 64 columns ----
__device__ __forceinline__ void stage_xt64(const float* __restrict__ xb,
                                           ushort_t* __restrict__ xt, int tid) {
  const int col = tid & 63;
  const int hi = tid >> 6;  // 0..3
  const float* p = xb + col;
#pragma unroll
  for (int i = 0; i < 4; ++i) {
    const int c0 = hi * 32 + i * 8;
    ushort_t u[8] __attribute__((aligned(16)));
#pragma unroll
    for (int j = 0; j < 8; ++j) u[j] = f2bf(p[(size_t)(c0 + j) * NK]);
    *(uint4*)(xt + col * XSTRIDE + c0) = *(const uint4*)u;
  }
}

// ---------------- K1 v3: conv + stats + materialize h (fp16, padded rows) ----------------
// 64-pos tile, 18.4KB LDS. Conv output kept in 16 regs (static idx), then after the
// post-MFMA barrier the (dead) xt tile is reused as an h staging buffer so the global
// h-store is ONE contiguous 17,408B coalesced copy -> full-line writes, no RFO.
// Stats computed from the fp16-ROUNDED h (keeps the BN-mean==0 identity in k_fold).
__global__ __launch_bounds__(256, 6) void k_stats2(const float* __restrict__ x,
    const ushort_t* __restrict__ w0b, float* __restrict__ sumP,
    float* __restrict__ sqP, ushort_t* __restrict__ hg) {
  __shared__ ushort_t xt[64 * XSTRIDE] __attribute__((aligned(16)));
  __shared__ float ssum[128], ssq[128];
  const int b = blockIdx.y;
  const int tid = threadIdx.x;
  stage_xt64(x + (size_t)b * NC * NK + (size_t)blockIdx.x * 64, xt, tid);
  __syncthreads();
  const int lane = tid & 63, w = tid >> 6;
  const int m = lane & 15, quad = lane >> 4;

  uint2 hreg[8];  // [p*4+t], statically indexed (fully unrolled loops)

#pragma unroll
  for (int p = 0; p < 2; ++p) {
    const int ch0 = (w + p * 4) * 16;
    bf16x8 wf[4];
#pragma unroll
    for (int kb = 0; kb < 4; ++kb)
      wf[kb] = *(const bf16x8*)(w0b + (ch0 + m) * 128 + kb * 32 + quad * 8);
    float s0 = 0.f, s1 = 0.f, s2 = 0.f, s3 = 0.f;
    float q0 = 0.f, q1 = 0.f, q2 = 0.f, q3 = 0.f;
#pragma unroll
    for (int t = 0; t < 4; ++t) {
      const ushort_t* xr = xt + (t * 16 + m) * XSTRIDE;
      f32x4 acc = {0.f, 0.f, 0.f, 0.f};
#pragma unroll
      for (int kb = 0; kb < 4; ++kb) {
        bf16x8 bx = *(const bf16x8*)(xr + kb * 32 + quad * 8);
        acc = mfma_bf16(wf[kb], bx, acc);
      }
      const ushort_t u0 = f2h(acc[0]), u1 = f2h(acc[1]);
      const ushort_t u2 = f2h(acc[2]), u3 = f2h(acc[3]);
      uint2 pk;
      pk.x = (uint_t)u0 | ((uint_t)u1 << 16);
      pk.y = (uint_t)u2 | ((uint_t)u3 << 16);
      hreg[p * 4 + t] = pk;
      const float r0 = h2f(u0), r1 = h2f(u1), r2 = h2f(u2), r3 = h2f(u3);
      s0 += r0; s1 += r1; s2 += r2; s3 += r3;
      q0 = fmaf(r0, r0, q0); q1 = fmaf(r1, r1, q1);
      q2 = fmaf(r2, r2, q2); q3 = fmaf(r3, r3, q3);
    }
    // positions live across the 16 m-lanes: butterfly over lane bits 0..3
#pragma unroll
    for (int d = 1; d < 16; d <<= 1) {
      s0 += __shfl_xor(s0, d); s1 += __shfl_xor(s1, d);
      s2 += __shfl_xor(s2, d); s3 += __shfl_xor(s3, d);
      q0 += __shfl_xor(q0, d); q1 += __shfl_xor(q1, d);
      q2 += __shfl_xor(q2, d); q3 += __shfl_xor(q3, d);
    }
    if (m == 0) {  // strips disjoint across (w,p,quad) -> plain stores
      ssum[ch0 + quad * 4 + 0] = s0; ssum[ch0 + quad * 4 + 1] = s1;
      ssum[ch0 + quad * 4 + 2] = s2; ssum[ch0 + quad * 4 + 3] = s3;
      ssq[ch0 + quad * 4 + 0] = q0; ssq[ch0 + quad * 4 + 1] = q1;
      ssq[ch0 + quad * 4 + 2] = q2; ssq[ch0 + quad * 4 + 3] = q3;
    }
  }
  __syncthreads();  // all xt reads done; ssum/ssq visible

  // phase C: scatter h fragments into the dead xt tile (LDS, cheap)
#pragma unroll
  for (int p = 0; p < 2; ++p) {
    const int ch0 = (w + p * 4) * 16;
#pragma unroll
    for (int t = 0; t < 4; ++t)
      *(uint2*)(xt + (t * 16 + m) * XSTRIDE + ch0 + quad * 4) = hreg[p * 4 + t];
  }
  __syncthreads();

  // phase D: one contiguous coalesced 17,408B store LDS -> global
  {
    const uint4* src = (const uint4*)xt;
    uint4* dst =
        (uint4*)(hg + ((size_t)b * NK + (size_t)blockIdx.x * 64) * XSTRIDE);
#pragma unroll
    for (int i = 0; i < 4; ++i) dst[i * 256 + tid] = src[i * 256 + tid];
    if (tid < 64) dst[1024 + tid] = src[1024 + tid];
  }

  if (tid < 128) {
    const int bucket = blockIdx.x & 31;
    atomicAdd(&sumP[bucket * 1024 + b * 128 + tid], ssum[tid]);
    atomicAdd(&sqP[bucket * 1024 + b * 128 + tid], ssq[tid]);
  }
}

// ---------------- K2: reduce buckets, fold IN+BN into per-(b,c) alpha/beta ----------------
__global__ void k_fold(const float* __restrict__ ws_in, const float* __restrict__ bn_g,
                       const float* __restrict__ bn_b, float* __restrict__ alpha,
                       float* __restrict__ beta) {
  int c = threadIdx.x;  // 128 threads
  const float* sumP = ws_in + WSF_SUMP;
  const float* sqP = ws_in + WSF_SQP;
  float var[NB], muv[NB];
  float bvar = 0.f;
#pragma unroll 1
  for (int b = 0; b < NB; ++b) {
    float s = 0.f, q = 0.f;
#pragma unroll
    for (int k = 0; k < 32; ++k) {
      s += sumP[k * 1024 + b * 128 + c];
      q += sqP[k * 1024 + b * 128 + c];
    }
    float mu = s * (1.f / NK);
    float v = q * (1.f / NK) - mu * mu;
    muv[b] = mu;
    var[b] = v;
    bvar += v / (v + IN_EPS);
  }
  bvar *= 0.125f;
  float s2 = rsqrtf(bvar + BN_EPS);
  float g = bn_g[c], bb = bn_b[c];
#pragma unroll
  for (int b = 0; b < NB; ++b) {
    float a = rsqrtf(var[b] + IN_EPS) * s2 * g;
    alpha[b * 128 + c] = a;
    beta[b * 128 + c] = bb - muv[b] * a;
  }
}

// ---------------- K3 v3: load h -> in-LDS norm -> qkv+softmax+agg (fp16 MFMA) ----------------
// launch_bounds(256,4): 128-VGPR budget -- the 12 f16x8 weight frags + af + accs
// need ~100 VGPRs; the (256,8) declaration in v2 forced spills in the MFMA loop.
__global__ __launch_bounds__(256, 4) void k_fused2(
    const ushort_t* __restrict__ hg, const float* __restrict__ x_row,
    const ushort_t* __restrict__ wb, const float* __restrict__ alpha,
    const float* __restrict__ beta, const float* __restrict__ bq,
    const float* __restrict__ bk, const float* __restrict__ bv,
    const float* __restrict__ g1p, float* __restrict__ out) {
  __shared__ ushort_t xt[64 * XSTRIDE] __attribute__((aligned(16)));  // 17408 B
  __shared__ float souts[128 * 5];                                    // 2560 B
  const int b = blockIdx.y;
  const int tid = threadIdx.x;
  const int lane = tid & 63, w = tid >> 6;

  // stage: 1088 uint4s (17,408 B), contiguous & coalesced, reg-staged
  {
    const uint4* src =
        (const uint4*)(hg + ((size_t)b * NK + (size_t)blockIdx.x * 64) * XSTRIDE);
    uint4* dst = (uint4*)xt;
#pragma unroll
    for (int i = 0; i < 4; ++i) dst[i * 256 + tid] = src[i * 256 + tid];
    if (tid < 64) dst[1024 + tid] = src[1024 + tid];
  }
  const float g1 = g1p[0];
  __syncthreads();

  // ---- in-LDS normalization: h = relu(alpha*h + beta), fp16 in/out ----
  {
    const int pos = tid & 63;
    const int cg = __builtin_amdgcn_readfirstlane(tid >> 6);  // wave-uniform
    ushort_t* row = xt + pos * XSTRIDE + cg * 32;
    const float* ap = alpha + b * 128 + cg * 32;
    const float* bp = beta + b * 128 + cg * 32;
#pragma unroll
    for (int i = 0; i < 4; ++i) {
      uint4 v = *(const uint4*)(row + i * 8);
      uint_t rr[4] = {v.x, v.y, v.z, v.w};
      uint_t ow[4];
#pragma unroll
      for (int j = 0; j < 4; ++j) {
        const int c = i * 8 + j * 2;
        float lo = h2f((ushort_t)(rr[j] & 0xffffu));
        float hi = h2f((ushort_t)(rr[j] >> 16));
        float nlo = fmaxf(fmaf(lo, ap[c], bp[c]), 0.f);
        float nhi = fmaxf(fmaf(hi, ap[c + 1], bp[c + 1]), 0.f);
        ow[j] = (uint_t)f2h(nlo) | ((uint_t)f2h(nhi) << 16);
      }
      uint4 o;
      o.x = ow[0]; o.y = ow[1]; o.z = ow[2]; o.w = ow[3];
      *(uint4*)(row + i * 8) = o;
    }
  }
  __syncthreads();

  // ---- QKV phase (fp16) ----
  const int m = lane & 15, quad = lane >> 4;
  const ushort_t* wqb = wb + 16384;
  const ushort_t* wkb = wb + 32768;
  const ushort_t* wvb = wb + 49152;
#pragma unroll 1
  for (int p = 0; p < 2; ++p) {
    const int ch0 = (w + p * 4) * 16;
    f16x8 wqf[4], wkf[4], wvf[4];
#pragma unroll
    for (int kb = 0; kb < 4; ++kb) {
      wqf[kb] = *(const f16x8*)(wqb + (ch0 + m) * 128 + kb * 32 + quad * 8);
      wkf[kb] = *(const f16x8*)(wkb + (ch0 + m) * 128 + kb * 32 + quad * 8);
      wvf[kb] = *(const f16x8*)(wvb + (ch0 + m) * 128 + kb * 32 + quad * 8);
    }
    const float bqv = bq[ch0 + m];
    const float bkv = bk[ch0 + m];
    const float bvv = bv[ch0 + m];
#pragma unroll 1
    for (int t = 0; t < 4; ++t) {
      const ushort_t* hr = xt + (t * 16 + m) * XSTRIDE;
      f16x8 af[4];
#pragma unroll
      for (int kb = 0; kb < 4; ++kb)
        af[kb] = *(const f16x8*)(hr + kb * 32 + quad * 8);
      f32x4 qa = {0.f, 0.f, 0.f, 0.f};
      f32x4 ka = {0.f, 0.f, 0.f, 0.f};
#pragma unroll
      for (int kb = 0; kb < 4; ++kb) qa = mfma_f16(af[kb], wqf[kb], qa);
#pragma unroll
      for (int kb = 0; kb < 4; ++kb) ka = mfma_f16(af[kb], wkf[kb], ka);
      // D: col=lane&15 -> outch-in-strip, row=quad*4+r -> neighbor
      float p0 = (qa[0] + bqv) * (ka[0] + bkv);
      float p1 = (qa[1] + bqv) * (ka[1] + bkv);
      float p2 = (qa[2] + bqv) * (ka[2] + bkv);
      float p3 = (qa[3] + bqv) * (ka[3] + bkv);
      float mx = fmaxf(fmaxf(p0, p1), fmaxf(p2, p3));
      mx = fmaxf(mx, __shfl_xor(mx, 16));
      mx = fmaxf(mx, __shfl_xor(mx, 32));
      float e0 = __expf(p0 - mx), e1 = __expf(p1 - mx);
      float e2 = __expf(p2 - mx), e3 = __expf(p3 - mx);
      float sm = (e0 + e1) + (e2 + e3);
      sm += __shfl_xor(sm, 16);
      sm += __shfl_xor(sm, 32);
      f32x4 va = {0.f, 0.f, 0.f, 0.f};
#pragma unroll
      for (int kb = 0; kb < 4; ++kb) va = mfma_f16(af[kb], wvf[kb], va);
      float r0 = e0 * (va[0] + bvv) + e1 * (va[1] + bvv) +
                 e2 * (va[2] + bvv) + e3 * (va[3] + bvv);
      r0 += __shfl_xor(r0, 16);
      r0 += __shfl_xor(r0, 32);
      if (quad == 0) souts[(ch0 + m) * 5 + t] = r0 / sm;
    }
  }
  __syncthreads();

  // ---- coalesced epilogue: out = x_row + g1 * souts ----
  if (tid < 128) {
    const int c = tid;
    const size_t oi = ((size_t)b * NC + c) * NPOS + blockIdx.x * 4;
    const float4 xr = *(const float4*)(x_row + oi);
    const float* sp = souts + c * 5;
    float4 o;
    o.x = xr.x + g1 * sp[0];
    o.y = xr.y + g1 * sp[1];
    o.z = xr.z + g1 * sp[2];
    o.w = xr.w + g1 * sp[3];
    *(float4*)(out + oi) = o;
  }
}

// =================== v1 fallback path (used only if workspace too small) ===================
__global__ __launch_bounds__(256, 4) void k_stats1(const float* __restrict__ x,
    const ushort_t* __restrict__ w0b, float* __restrict__ sumP,
    float* __restrict__ sqP) {
  __shared__ ushort_t xt[128 * XSTRIDE];
  __shared__ float ssum[128], ssq[128];
  const int b = blockIdx.y;
  const int tid = threadIdx.x;
  stage_xt128(x + (size_t)b * NC * NK + (size_t)blockIdx.x * 128, xt, tid);
  __syncthreads();
  const int lane = tid & 63, w = tid >> 6;
  const int m = lane & 15, quad = lane >> 4;

#pragma unroll 1
  for (int p = 0; p < 2; ++p) {
    const int ch0 = (w + p * 4) * 16;
    bf16x8 wf[4];
#pragma unroll
    for (int kb = 0; kb < 4; ++kb)
      wf[kb] = *(const bf16x8*)(w0b + (ch0 + m) * 128 + kb * 32 + quad * 8);
    float s = 0.f, q2 = 0.f;
#pragma unroll 2
    for (int t = 0; t < 8; ++t) {
      const ushort_t* xr = xt + (t * 16 + m) * XSTRIDE;
      f32x4 acc = {0.f, 0.f, 0.f, 0.f};
#pragma unroll
      for (int kb = 0; kb < 4; ++kb) {
        bf16x8 af = *(const bf16x8*)(xr + kb * 32 + quad * 8);
        acc = mfma_bf16(af, wf[kb], acc);
      }
      s += (acc[0] + acc[1]) + (acc[2] + acc[3]);
      q2 += (acc[0] * acc[0] + acc[1] * acc[1]) +
            (acc[2] * acc[2] + acc[3] * acc[3]);
    }
    s += __shfl_xor(s, 16);
    s += __shfl_xor(s, 32);
    q2 += __shfl_xor(q2, 16);
    q2 += __shfl_xor(q2, 32);
    if (quad == 0) {
      ssum[ch0 + m] = s;
      ssq[ch0 + m] = q2;
    }
  }
  __syncthreads();
  if (tid < 128) {
    const int bucket = blockIdx.x & 31;
    atomicAdd(&sumP[bucket * 1024 + b * 128 + tid], ssum[tid]);
    atomicAdd(&sqP[bucket * 1024 + b * 128 + tid], ssq[tid]);
  }
}

__global__ __launch_bounds__(256, 4) void k_fused1(const float* __restrict__ x,
    const float* __restrict__ x_row, const ushort_t* __restrict__ wb,
    const float* __restrict__ alpha, const float* __restrict__ beta,
    const float* __restrict__ bq, const float* __restrict__ bk,
    const float* __restrict__ bv, const float* __restrict__ g1p,
    float* __restrict__ out) {
  __shared__ ushort_t xt[64 * XSTRIDE];
  __shared__ ushort_t ht[64 * XSTRIDE];
  __shared__ float souts[128 * 5];
  const int b = blockIdx.y;
  const int tid = threadIdx.x;
  stage_xt64(x + (size_t)b * NC * NK + (size_t)blockIdx.x * 64, xt, tid);
  const float g1 = g1p[0];
  __syncthreads();
  const int lane = tid & 63, w = tid >> 6;
  const int m = lane & 15, quad = lane >> 4;
  const ushort_t* w0b = wb;
  const ushort_t* wqb = wb + 16384;
  const ushort_t* wkb = wb + 32768;
  const ushort_t* wvb = wb + 49152;

#pragma unroll 1
  for (int p = 0; p < 2; ++p) {
    const int ch0 = (w + p * 4) * 16;
    bf16x8 wf[4];
#pragma unroll
    for (int kb = 0; kb < 4; ++kb)
      wf[kb] = *(const bf16x8*)(w0b + (ch0 + m) * 128 + kb * 32 + quad * 8);
    const float4 av = *(const float4*)(alpha + b * 128 + ch0 + quad * 4);
    const float4 bev = *(const float4*)(beta + b * 128 + ch0 + quad * 4);
#pragma unroll
    for (int t = 0; t < 4; ++t) {
      const ushort_t* xr = xt + (t * 16 + m) * XSTRIDE;
      f32x4 acc = {0.f, 0.f, 0.f, 0.f};
#pragma unroll
      for (int kb = 0; kb < 4; ++kb) {
        bf16x8 bx = *(const bf16x8*)(xr + kb * 32 + quad * 8);
        acc = mfma_bf16(wf[kb], bx, acc);
      }
      float h0 = fmaxf(acc[0] * av.x + bev.x, 0.f);
      float h1 = fmaxf(acc[1] * av.y + bev.y, 0.f);
      float h2 = fmaxf(acc[2] * av.z + bev.z, 0.f);
      float h3 = fmaxf(acc[3] * av.w + bev.w, 0.f);
      uint2 pk;
      pk.x = (uint_t)f2bf(h0) | ((uint_t)f2bf(h1) << 16);
      pk.y = (uint_t)f2bf(h2) | ((uint_t)f2bf(h3) << 16);
      *(uint2*)(ht + (t * 16 + m) * XSTRIDE + ch0 + quad * 4) = pk;
    }
  }
  __syncthreads();

#pragma unroll 1
  for (int p = 0; p < 2; ++p) {
    const int ch0 = (w + p * 4) * 16;
    bf16x8 wqf[4], wkf[4], wvf[4];
#pragma unroll
    for (int kb = 0; kb < 4; ++kb) {
      wqf[kb] = *(const bf16x8*)(wqb + (ch0 + m) * 128 + kb * 32 + quad * 8);
      wkf[kb] = *(const bf16x8*)(wkb + (ch0 + m) * 128 + kb * 32 + quad * 8);
      wvf[kb] = *(const bf16x8*)(wvb + (ch0 + m) * 128 + kb * 32 + quad * 8);
    }
    const float bqv = bq[ch0 + m];
    const float bkv = bk[ch0 + m];
    const float bvv = bv[ch0 + m];
#pragma unroll 1
    for (int t = 0; t < 4; ++t) {
      const ushort_t* hr = ht + (t * 16 + m) * XSTRIDE;
      bf16x8 af[4];
#pragma unroll
      for (int kb = 0; kb < 4; ++kb)
        af[kb] = *(const bf16x8*)(hr + kb * 32 + quad * 8);
      f32x4 qa = {0.f, 0.f, 0.f, 0.f};
      f32x4 ka = {0.f, 0.f, 0.f, 0.f};
#pragma unroll
      for (int kb = 0; kb < 4; ++kb) qa = mfma_bf16(af[kb], wqf[kb], qa);
#pragma unroll
      for (int kb = 0; kb < 4; ++kb) ka = mfma_bf16(af[kb], wkf[kb], ka);
      float p0 = (qa[0] + bqv) * (ka[0] + bkv);
      float p1 = (qa[1] + bqv) * (ka[1] + bkv);
      float p2 = (qa[2] + bqv) * (ka[2] + bkv);
      float p3 = (qa[3] + bqv) * (ka[3] + bkv);
      float mx = fmaxf(fmaxf(p0, p1), fmaxf(p2, p3));
      mx = fmaxf(mx, __shfl_xor(mx, 16));
      mx = fmaxf(mx, __shfl_xor(mx, 32));
      float e0 = __expf(p0 - mx), e1 = __expf(p1 - mx);
      float e2 = __expf(p2 - mx), e3 = __expf(p3 - mx);
      float sm = (e0 + e1) + (e2 + e3);
      sm += __shfl_xor(sm, 16);
      sm += __shfl_xor(sm, 32);
      f32x4 va = {0.f, 0.f, 0.f, 0.f};
#pragma unroll
      for (int kb = 0; kb < 4; ++kb) va = mfma_bf16(af[kb], wvf[kb], va);
      float r0 = e0 * (va[0] + bvv) + e1 * (va[1] + bvv) +
                 e2 * (va[2] + bvv) + e3 * (va[3] + bvv);
      r0 += __shfl_xor(r0, 16);
      r0 += __shfl_xor(r0, 32);
      if (quad == 0) souts[(ch0 + m) * 5 + t] = r0 / sm;
    }
  }
  __syncthreads();

  if (tid < 128) {
    const int c = tid;
    const size_t oi = ((size_t)b * NC + c) * NPOS + blockIdx.x * 4;
    const float4 xr = *(const float4*)(x_row + oi);
    const float* sp = souts + c * 5;
    float4 o;
    o.x = xr.x + g1 * sp[0];
    o.y = xr.y + g1 * sp[1];
    o.z = xr.z + g1 * sp[2];
    o.w = xr.w + g1 * sp[3];
    *(float4*)(out + oi) = o;
  }
}

extern "C" void kernel_launch(void* const* d_in, const int* in_sizes, int n_in,
                              void* d_out, int out_size, void* d_ws, size_t ws_size,
                              hipStream_t stream) {
  (void)in_sizes; (void)n_in; (void)out_size;
  const float* x_row   = (const float*)d_in[0];
  const float* x_local = (const float*)d_in[1];
  const float* w0   = (const float*)d_in[2];
  const float* bn_g = (const float*)d_in[4];
  const float* bn_b = (const float*)d_in[5];
  const float* wq   = (const float*)d_in[6];
  const float* bq   = (const float*)d_in[7];
  const float* wk   = (const float*)d_in[8];
  const float* bk   = (const float*)d_in[9];
  const float* wv   = (const float*)d_in[10];
  const float* bv   = (const float*)d_in[11];
  const float* gamma1 = (const float*)d_in[12];
  float* out = (float*)d_out;
  float* ws = (float*)d_ws;
  ushort_t* wb = (ushort_t*)((char*)d_ws + WSB_WEIGHTS);
  ushort_t* hg = (ushort_t*)((char*)d_ws + WSB_H);

  hipMemsetAsync(ws, 0, 65536 * sizeof(float), stream);  // bucketed accumulators

  if (ws_size >= WS_NEEDED) {
    k_prep<1><<<256, 256, 0, stream>>>(w0, wq, wk, wv, wb);
    k_stats2<<<dim3(500, NB), 256, 0, stream>>>(x_local, wb, ws + WSF_SUMP,
                                                ws + WSF_SQP, hg);
    k_fold<<<1, 128, 0, stream>>>(ws, bn_g, bn_b, ws + WSF_ALPHA, ws + WSF_BETA);
    k_fused2<<<dim3(500, NB), 256, 0, stream>>>(hg, x_row, wb, ws + WSF_ALPHA,
                                                ws + WSF_BETA, bq, bk, bv, gamma1,
                                                out);
  } else {
    // workspace too small for the h buffer: previous verified pipeline
    k_prep<0><<<256, 256, 0, stream>>>(w0, wq, wk, wv, wb);
    k_stats1<<<dim3(250, NB), 256, 0, stream>>>(x_local, wb, ws + WSF_SUMP,
                                                ws + WSF_SQP);
    k_fold<<<1, 128, 0, stream>>>(ws, bn_g, bn_b, ws + WSF_ALPHA, ws + WSF_BETA);
    k_fused1<<<dim3(500, NB), 256, 0, stream>>>(x_local, x_row, wb, ws + WSF_ALPHA,
                                                ws + WSF_BETA, bq, bk, bv, gamma1,
                                                out);
  }
}